// Round 15
// baseline (560.386 us; speedup 1.0000x reference)
//
#include <hip/hip_runtime.h>
#include <math.h>

typedef unsigned short u16;
typedef unsigned int u32;
typedef short bh8 __attribute__((ext_vector_type(8)));
typedef float f4 __attribute__((ext_vector_type(4)));

__device__ __forceinline__ float bs2f(u16 s){
  union {unsigned int u; float f;} v; v.u = ((unsigned int)s)<<16; return v.f;
}
__device__ __forceinline__ u16 f2bs(float f){
  union {float f; unsigned int u;} v; v.f = f;
  unsigned int u = v.u + 0x7fffu + ((v.u>>16)&1u);
  return (u16)(u>>16);
}

// ---------------------------------------------------------------- prep
__global__ void prep_all_k(
  const float* __restrict__ wq1,const float* __restrict__ wk1,const float* __restrict__ bq1,const float* __restrict__ bk1,
  const float* __restrict__ wq2,const float* __restrict__ wk2,const float* __restrict__ bq2,const float* __restrict__ bk2,
  const float* __restrict__ wp1,const float* __restrict__ wp2,
  const float* __restrict__ wv1,const float* __restrict__ wv2,
  const float* __restrict__ w1,const float* __restrict__ b1,const float* __restrict__ w2,const float* __restrict__ b2,
  u16* __restrict__ wqkT0,u16* __restrict__ wqkT1,u16* __restrict__ wpT0,u16* __restrict__ wpT1,
  u16* __restrict__ wvb0,u16* __restrict__ wvb1,
  u16* __restrict__ w1T,u16* __restrict__ w2T,
  float* __restrict__ bqkf0,float* __restrict__ bqkf1,float* __restrict__ b1f,float* __restrict__ b2f)
{
  int t = blockIdx.x*256 + threadIdx.x;
  const int S_wqk = 1536*384, S_wp = 8*384*384, S_w1 = 768*384, S_w2 = 384*768;
  if (t < 2*S_wqk){
    const float* wq = (t<S_wqk)? wq1:wq2; const float* wk = (t<S_wqk)? wk1:wk2;
    u16* o = (t<S_wqk)? wqkT0:wqkT1; int i = (t<S_wqk)? t : t-S_wqk;
    int d = i%384, cidx = i/384;
    int c2 = (cidx<768)? cidx : cidx-768;
    int h = c2/96, e = c2-h*96;
    const float* src = (cidx<768)? wq : wk;
    o[i] = f2bs(src[(h*384+d)*96 + e]);
    return;
  }
  t -= 2*S_wqk;
  if (t < 2*S_wp){   // wpT[h][fp][f] = wp[h*384+f][fp]
    const float* wp = (t<S_wp)? wp1:wp2; u16* o = (t<S_wp)? wpT0:wpT1;
    int i = (t<S_wp)? t: t-S_wp;
    int f = i%384; int r = i/384; int fp = r%384; int h = r/384;
    o[i] = f2bs(wp[(h*384+f)*384 + fp]);
    return;
  }
  t -= 2*S_wp;
  if (t < 2*S_wp){   // wvb = bf16 copy of wv [h][d][f]
    const float* wvs = (t<S_wp)? wv1:wv2; u16* o = (t<S_wp)? wvb0:wvb1;
    int i = (t<S_wp)? t: t-S_wp;
    o[i] = f2bs(wvs[i]);
    return;
  }
  t -= 2*S_wp;
  if (t < S_w1){ int d = t%384, hid = t/384; w1T[t] = f2bs(w1[d*768+hid]); return; }
  t -= S_w1;
  if (t < S_w2){ int hid = t%768, dd = t/768; w2T[t] = f2bs(w2[hid*384+dd]); return; }
  t -= S_w2;
  if (t < 1536){ bqkf0[t] = (t<768)? bq1[t] : bk1[t-768]; return; }
  t -= 1536;
  if (t < 1536){ bqkf1[t] = (t<768)? bq2[t] : bk2[t-768]; return; }
  t -= 1536;
  if (t < 768){ b1f[t] = b1[t]; return; }
  t -= 768;
  if (t < 384){ b2f[t] = b2[t]; return; }
}

// bcf[h][fp] = sum_f bv_h[f] * wp[h*384+f][fp]
__global__ void bcomb_k(const float* __restrict__ bv, const float* __restrict__ wp, float* __restrict__ out)
{
  int i = blockIdx.x*256 + threadIdx.x;
  if (i >= 3072) return;
  int h = i/384, fp = i-h*384;
  float s = 0.f;
  for (int f=0; f<384; f++) s += bv[h*384+f] * wp[(h*384+f)*384 + fp];
  out[i] = s;
}

// decoder f32 [B,C,1024] -> xf f32 [B,1024,C] + xb bf16
__global__ void t0_k(const float* __restrict__ dec, float* __restrict__ xf, u16* __restrict__ xb)
{
  int b = blockIdx.z, c0 = blockIdx.y*64, n0 = blockIdx.x*64;
  __shared__ float ts[64][65];
  for (int it=threadIdx.x; it<4096; it+=256){
    int r = it>>6, cc = it&63;
    ts[r][cc] = dec[((long)(b*384 + c0+r)<<10) + n0+cc];
  }
  __syncthreads();
  for (int it=threadIdx.x; it<4096; it+=256){
    int r = it>>6, cc = it&63;
    float s = ts[cc][r];
    long o = ((long)((b<<10)+n0+r))*384 + c0+cc;
    xb[o] = f2bs(s); xf[o] = s;
  }
}

// ---------------------------------------------------------------- generic bf16 MFMA GEMM, 128x128 tile, BK=64
// m97 staging: global_load_lds width-16, pre-swizzled source, swizzled ds_read.
template<int EPI>
__global__ __launch_bounds__(256,2) void gemm_k(
    const u16* __restrict__ A, int lda, long sA,
    const u16* __restrict__ BT, int ldb, long sB,
    const float* __restrict__ bias,
    void* __restrict__ out0, void* __restrict__ out1,
    long sO, int K, int ldc)
{
  __shared__ __align__(16) u16 As[128*64];
  __shared__ __align__(16) u16 Bs[128*64];
  __shared__ __align__(16) u16 Cs[(EPI==2)?128*144:8];
  const int z = blockIdx.z;
  const u16* Ab = A + (long)z*sA;
  const u16* Bb = BT + (long)z*sB;
  const int m0 = blockIdx.x*128, n0 = blockIdx.y*128;
  const int tid = threadIdx.x, lane = tid&63, wv = tid>>6;
  const int wr = wv>>1, wc = wv&1;
  const int stg_r = lane>>3;
  const int stg_u = (lane&7) ^ (lane>>3);
  f4 acc[4][4];
  #pragma unroll
  for (int i=0;i<4;i++)
    #pragma unroll
    for (int j=0;j<4;j++) acc[i][j] = (f4){0.f,0.f,0.f,0.f};
  for (int k0=0;k0<K;k0+=64){
    __syncthreads();
    #pragma unroll
    for (int q=0;q<4;q++){
      int rg = (wv*4+q)*8 + stg_r;
      const u16* ga = Ab + (long)(m0+rg)*lda + k0 + stg_u*8;
      const u16* gb = Bb + (long)(n0+rg)*ldb + k0 + stg_u*8;
      __builtin_amdgcn_global_load_lds(
        (const __attribute__((address_space(1))) unsigned int*)ga,
        (__attribute__((address_space(3))) unsigned int*)(As + (wv*4+q)*512), 16, 0, 0);
      __builtin_amdgcn_global_load_lds(
        (const __attribute__((address_space(1))) unsigned int*)gb,
        (__attribute__((address_space(3))) unsigned int*)(Bs + (wv*4+q)*512), 16, 0, 0);
    }
    __syncthreads();
    #pragma unroll
    for (int ts=0;ts<2;ts++){
      const int sl = ((ts*4 + (lane>>4)) ^ (lane&7))*8;
      bh8 af[4], bfr[4];
      #pragma unroll
      for (int i=0;i<4;i++) af[i] = *(const bh8*)&As[(wr*64+i*16+(lane&15))*64 + sl];
      #pragma unroll
      for (int j=0;j<4;j++) bfr[j] = *(const bh8*)&Bs[(wc*64+j*16+(lane&15))*64 + sl];
      #pragma unroll
      for (int i=0;i<4;i++)
        #pragma unroll
        for (int j=0;j<4;j++)
          acc[i][j] = __builtin_amdgcn_mfma_f32_16x16x32_bf16(af[i], bfr[j], acc[i][j], 0,0,0);
    }
  }
  if constexpr (EPI==0){           // plain bf16 row-major
    u16* O = (u16*)out0 + (long)z*sO;
    #pragma unroll
    for (int i=0;i<4;i++)
      #pragma unroll
      for (int j=0;j<4;j++)
        #pragma unroll
        for (int r=0;r<4;r++){
          int m = m0 + wr*64 + i*16 + ((lane>>4)<<2) + r;
          int n = n0 + wc*64 + j*16 + (lane&15);
          O[(long)m*ldc + n] = f2bs(acc[i][j][r]);
        }
  } else if constexpr (EPI==1){    // QK scatter, +bias
    u16* Q = (u16*)out0; u16* Ko = (u16*)out1;
    #pragma unroll
    for (int j=0;j<4;j++){
      int n = n0 + wc*64 + j*16 + (lane&15);
      float bv = bias[n];
      bool isQ = n < 768; int cc = isQ ? n : n-768;
      int h = cc/96, e = cc - h*96;
      u16* dst = isQ ? Q : Ko;
      #pragma unroll
      for (int i=0;i<4;i++)
        #pragma unroll
        for (int r=0;r<4;r++){
          int m = m0 + wr*64 + i*16 + ((lane>>4)<<2) + r;
          int bb = m>>10, nn = m&1023;
          dst[((long)((bb*8+h)*1024 + nn))*96 + e] = f2bs(acc[i][j][r]+bv);
        }
    }
  } else if constexpr (EPI==2){    // transpose-store Yt[b][f][h*1024+m], +bias (bcf)
    __syncthreads();
    #pragma unroll
    for (int j=0;j<4;j++){
      int nl = wc*64 + j*16 + (lane&15);
      float bv = bias[n0+nl];
      #pragma unroll
      for (int i=0;i<4;i++)
        #pragma unroll
        for (int r=0;r<4;r++){
          int ml = wr*64 + i*16 + ((lane>>4)<<2) + r;
          Cs[nl*144 + ml] = f2bs(acc[i][j][r]+bv);
        }
    }
    __syncthreads();
    u16* O = (u16*)out0;
    const int bb = m0>>10, mb = m0&1023;
    #pragma unroll
    for (int p=0;p<8;p++){
      int row = p*16 + (tid>>4), mcol = (tid&15)*8;
      bh8 vv = *(const bh8*)&Cs[row*144 + mcol];
      int n = n0 + row; int h = n/384, f = n - h*384;
      *(bh8*)(O + (long)bb*3145728 + (long)f*8192 + h*1024 + mb + mcol) = vv;
    }
  } else if constexpr (EPI==3){    // +bias, exact gelu, bf16 row-major
    u16* O = (u16*)out0;
    #pragma unroll
    for (int j=0;j<4;j++){
      int n = n0 + wc*64 + j*16 + (lane&15);
      float bv = bias[n];
      #pragma unroll
      for (int i=0;i<4;i++)
        #pragma unroll
        for (int r=0;r<4;r++){
          int m = m0 + wr*64 + i*16 + ((lane>>4)<<2) + r;
          float v = acc[i][j][r] + bv;
          v = 0.5f*v*(1.0f + erff(v*0.70710678118f));
          O[(long)m*ldc + n] = f2bs(v);
        }
    }
  } else {                         // EPI==4: +bias, f32 row-major
    float* O = (float*)out0;
    #pragma unroll
    for (int j=0;j<4;j++){
      int n = n0 + wc*64 + j*16 + (lane&15);
      float bv = bias[n];
      #pragma unroll
      for (int i=0;i<4;i++)
        #pragma unroll
        for (int r=0;r<4;r++){
          int m = m0 + wr*64 + i*16 + ((lane>>4)<<2) + r;
          O[(long)m*ldc + n] = acc[i][j][r] + bv;
        }
    }
  }
}

// ---------------------------------------------------------------- gemm_s: S2[b][n][h*1024+m] = sigmoid(scale * Q.K)
__global__ __launch_bounds__(256,2) void gemm_s_k(
  const u16* __restrict__ q, const u16* __restrict__ kk_, u16* __restrict__ S2)
{
  __shared__ __align__(16) u16 smem[128*136];
  u16* As = smem;
  u16* Bs = smem + 128*56;
  const int wg = blockIdx.x;
  const int b = wg&7, idx = wg>>3;
  const int h = idx>>6, rem = idx&63;
  const int m0 = (rem>>3)*128;
  const int n0 = (rem&7)*128;
  const u16* Ab = q   + ((long)(b*8+h)<<10)*96;
  const u16* Bb = kk_ + ((long)(b*8+h)<<10)*96;
  const int tid = threadIdx.x, lane = tid&63, wv = tid>>6;
  const int wr = wv>>1, wc = wv&1;
  f4 acc[4][4];
  #pragma unroll
  for (int i=0;i<4;i++)
    #pragma unroll
    for (int j=0;j<4;j++) acc[i][j] = (f4){0.f,0.f,0.f,0.f};
  for (int k0=0;k0<96;k0+=32){
    __syncthreads();
    #pragma unroll
    for (int u=0;u<2;u++){
      int c = tid + u*256;
      int row = c>>2, col8 = (c&3)*8;
      *(bh8*)&As[row*56+col8] = *(const bh8*)(Ab + (long)(m0+row)*96 + k0 + col8);
      *(bh8*)&Bs[row*56+col8] = *(const bh8*)(Bb + (long)(n0+row)*96 + k0 + col8);
    }
    __syncthreads();
    bh8 af[4], bfr[4];
    #pragma unroll
    for (int i=0;i<4;i++) af[i] = *(const bh8*)&As[(wr*64+i*16+(lane&15))*56 + (lane>>4)*8];
    #pragma unroll
    for (int j=0;j<4;j++) bfr[j] = *(const bh8*)&Bs[(wc*64+j*16+(lane&15))*56 + (lane>>4)*8];
    #pragma unroll
    for (int i=0;i<4;i++)
      #pragma unroll
      for (int j=0;j<4;j++)
        acc[i][j] = __builtin_amdgcn_mfma_f32_16x16x32_bf16(af[i], bfr[j], acc[i][j], 0,0,0);
  }
  const float scale = 0.1020620726f;  // 1/sqrt(96)
  __syncthreads();
  #pragma unroll
  for (int j=0;j<4;j++){
    int col = wc*64 + j*16 + (lane&15);
    #pragma unroll
    for (int i=0;i<4;i++)
      #pragma unroll
      for (int r=0;r<4;r++){
        int row = wr*64 + i*16 + ((lane>>4)<<2) + r;
        float y = acc[i][j][r]*scale;
        float sg = __builtin_amdgcn_rcpf(1.0f + __expf(-y));
        smem[row*136 + col] = f2bs(sg);
      }
  }
  __syncthreads();
  u16* O = S2 + (long)b*8388608 + (long)h*1024;
  #pragma unroll
  for (int p=0;p<8;p++){
    int c = tid + p*256;
    int row = c>>4, u = c&15;
    *(bh8*)(O + (long)(m0+row)*8192 + n0 + u*8) = *(const bh8*)&smem[row*136 + u*8];
  }
}

// ---------------------------------------------------------------- init: xo = a*x + bp   (f32 elementwise)
__global__ void init_k(const float* __restrict__ xin, const float* __restrict__ av,
                       const float* __restrict__ bpv, float* __restrict__ xo)
{
  int i = blockIdx.x*256 + threadIdx.x;
  long idx = (long)i*4;
  int c = (int)(idx % 384);
  f4 x = *(const f4*)(xin + idx);
  f4 o;
  #pragma unroll
  for (int kk=0;kk<4;kk++) o[kk] = av[c+kk]*x[kk] + bpv[c+kk];
  *(f4*)(xo + idx) = o;
}

// ---------------------------------------------------------------- gemm_big: xo += S2[b] @ YtAug[b]^T  (split-K=4, atomic)
// Full-N tile 128x384, 512 threads / 8 waves (2m x 4n), BK=64.
// grid 256 1D: b=wg&7 (XCD pin), t=wg>>3: ks=t&3, mt=t>>2.
__global__ __launch_bounds__(512,1) void gemm_big_k(
  const u16* __restrict__ S2, const u16* __restrict__ Yt, float* __restrict__ xo)
{
  __shared__ __align__(16) u16 As[128*64];   // 16KB
  __shared__ __align__(16) u16 Bs[384*64];   // 48KB
  const int wg = blockIdx.x;
  const int b = wg&7, t = wg>>3;
  const int ks = t&3, mt = t>>2;
  const int m0 = mt*128, kb0 = ks*2048;
  const u16* Ab = S2 + (long)b*8388608;   // [1024][8192]
  const u16* Bb = Yt + (long)b*3145728;   // [384][8192]
  const int tid = threadIdx.x, lane = tid&63, wv = tid>>6;   // wv 0..7
  const int wr = wv>>2, wcn = wv&3;                          // 2m x 4n
  const int stg_r = lane>>3;
  const int stg_u = (lane&7) ^ (lane>>3);
  f4 acc[4][6];
  #pragma unroll
  for (int i=0;i<4;i++)
    #pragma unroll
    for (int j=0;j<6;j++) acc[i][j] = (f4){0.f,0.f,0.f,0.f};
  for (int k0=kb0; k0<kb0+2048; k0+=64){
    __syncthreads();
    #pragma unroll
    for (int q=0;q<2;q++){   // A: 128 rows, 16 wave-instr total
      int rg = (wv*2+q)*8 + stg_r;
      const u16* ga = Ab + (((long)(m0+rg))<<13) + k0 + stg_u*8;
      __builtin_amdgcn_global_load_lds(
        (const __attribute__((address_space(1))) unsigned int*)ga,
        (__attribute__((address_space(3))) unsigned int*)(As + (wv*2+q)*512), 16, 0, 0);
    }
    #pragma unroll
    for (int q=0;q<6;q++){   // B: 384 rows, 48 wave-instr total
      int rg = (wv*6+q)*8 + stg_r;
      const u16* gb = Bb + (((long)rg)<<13) + k0 + stg_u*8;
      __builtin_amdgcn_global_load_lds(
        (const __attribute__((address_space(1))) unsigned int*)gb,
        (__attribute__((address_space(3))) unsigned int*)(Bs + (wv*6+q)*512), 16, 0, 0);
    }
    __syncthreads();
    #pragma unroll
    for (int ts=0;ts<2;ts++){
      const int sl = ((ts*4 + (lane>>4)) ^ (lane&7))*8;
      bh8 af[4], bfr[6];
      #pragma unroll
      for (int i=0;i<4;i++) af[i] = *(const bh8*)&As[(wr*64+i*16+(lane&15))*64 + sl];
      #pragma unroll
      for (int j=0;j<6;j++) bfr[j] = *(const bh8*)&Bs[(wcn*96+j*16+(lane&15))*64 + sl];
      #pragma unroll
      for (int i=0;i<4;i++)
        #pragma unroll
        for (int j=0;j<6;j++)
          acc[i][j] = __builtin_amdgcn_mfma_f32_16x16x32_bf16(af[i], bfr[j], acc[i][j], 0,0,0);
    }
  }
  #pragma unroll
  for (int j=0;j<6;j++){
    int n = wcn*96 + j*16 + (lane&15);
    #pragma unroll
    for (int i=0;i<4;i++)
      #pragma unroll
      for (int r=0;r<4;r++){
        int m = m0 + wr*64 + i*16 + ((lane>>4)<<2) + r;
        long o = ((long)((b<<10)+m))*384 + n;
        atomicAdd(&xo[o], acc[i][j][r]);
      }
  }
}

// ---------------------------------------------------------------- peg+LN, wave-per-row, no LDS
__global__ __launch_bounds__(256) void peg_ln_k(
  const float* __restrict__ xin, const float* __restrict__ pw, const float* __restrict__ pb,
  const float* __restrict__ g, const float* __restrict__ bta,
  float* __restrict__ xo, u16* __restrict__ xbo)
{
  const int row = blockIdx.x*4 + (threadIdx.x>>6);
  const int lane = threadIdx.x&63;
  const int b = row>>10, n = row&1023;
  const int i = n>>5, j = n&31;
  const float* xb_ = xin + ((long)(b<<10))*384;
  float v[6]; float s1=0.f, s2=0.f;
  #pragma unroll
  for (int kk=0;kk<6;kk++){
    int c = lane + kk*64;
    float sum = pb[c];
    #pragma unroll
    for (int di=-1; di<=1; di++){
      int ii = i+di; if (ii<0 || ii>31) continue;
      #pragma unroll
      for (int dj=-1; dj<=1; dj++){
        int jj = j+dj; if (jj<0 || jj>31) continue;
        sum += pw[c*9 + (di+1)*3 + (dj+1)] * xb_[(long)(ii*32+jj)*384 + c];
      }
    }
    v[kk] = sum; s1 += sum; s2 += sum*sum;
  }
  #pragma unroll
  for (int m=1;m<64;m<<=1){ s1 += __shfl_xor(s1,m); s2 += __shfl_xor(s2,m); }
  float mu = s1*(1.f/384.f);
  float var = s2*(1.f/384.f) - mu*mu;
  float rsq = rsqrtf(var + 1e-5f);
  long rb = (long)row*384;
  #pragma unroll
  for (int kk=0;kk<6;kk++){
    int c = lane + kk*64;
    float vv = (v[kk]-mu)*rsq*g[c] + bta[c];
    xo[rb+c] = vv; xbo[rb+c] = f2bs(vv);
  }
}

// row LN (f32 in) -> bf16 out
__global__ void ln_k(const float* __restrict__ x, const float* __restrict__ g,
                     const float* __restrict__ bb, u16* __restrict__ ob)
{
  long row = blockIdx.x; int l = threadIdx.x;
  const float* xr = x + row*384;
  float v[6]; float s1=0.f, s2=0.f;
  #pragma unroll
  for (int kk=0;kk<6;kk++){ int c=l+kk*64; float t=xr[c]; v[kk]=t; s1+=t; s2+=t*t; }
  #pragma unroll
  for (int m=1;m<64;m<<=1){ s1 += __shfl_xor(s1,m); s2 += __shfl_xor(s2,m); }
  float mu = s1*(1.f/384.f);
  float var = s2*(1.f/384.f) - mu*mu;
  float rsq = rsqrtf(var + 1e-5f);
  u16* orow = ob + row*384;
  #pragma unroll
  for (int kk=0;kk<6;kk++){ int c=l+kk*64; orow[c] = f2bs((v[kk]-mu)*rsq*g[c] + bb[c]); }
}

// v = a3*x + h2 ; LN2 ; write f32 vbuf
__global__ void f1_k(const float* __restrict__ xf2, const float* __restrict__ h2f,
                     const float* __restrict__ a3, const float* __restrict__ g,
                     const float* __restrict__ bb, float* __restrict__ vb)
{
  long row = blockIdx.x; int l = threadIdx.x;
  const float* xr = xf2 + row*384; const float* hr = h2f + row*384;
  float v[6]; float s1=0.f, s2=0.f;
  #pragma unroll
  for (int kk=0;kk<6;kk++){ int c=l+kk*64; float t = a3[c]*xr[c] + hr[c]; v[kk]=t; s1+=t; s2+=t*t; }
  #pragma unroll
  for (int m=1;m<64;m<<=1){ s1 += __shfl_xor(s1,m); s2 += __shfl_xor(s2,m); }
  float mu = s1*(1.f/384.f);
  float var = s2*(1.f/384.f) - mu*mu;
  float rsq = rsqrtf(var + 1e-5f);
  float* orow = vb + row*384;
  #pragma unroll
  for (int kk=0;kk<6;kk++){ int c=l+kk*64; orow[c] = (v[kk]-mu)*rsq*g[c] + bb[c]; }
}

// vbuf [B,1024,384] f32 -> d_out [B,384,1024] f32
__global__ void f2_k(const float* __restrict__ v, float* __restrict__ o)
{
  int b = blockIdx.z, c0 = blockIdx.y*64, n0 = blockIdx.x*64;
  __shared__ float tile[64][65];
  for (int it=threadIdx.x; it<4096; it+=256){
    int r = it>>6, cc = it&63;
    tile[r][cc] = v[((long)((b<<10)+n0+r))*384 + c0+cc];
  }
  __syncthreads();
  for (int it=threadIdx.x; it<4096; it+=256){
    int r = it>>6, cc = it&63;
    o[((long)(b*384 + c0+r)<<10) + n0+cc] = tile[cc][r];
  }
}

// ---------------------------------------------------------------- launch
extern "C" void kernel_launch(void* const* d_in, const int* in_sizes, int n_in,
                              void* d_out, int out_size, void* d_ws, size_t ws_size,
                              hipStream_t stream)
{
  const float* dec  = (const float*)d_in[0];
  const float* wq1  = (const float*)d_in[1];  const float* bq1 = (const float*)d_in[2];
  const float* wk1  = (const float*)d_in[3];  const float* bk1 = (const float*)d_in[4];
  const float* wv1  = (const float*)d_in[5];  const float* bv1 = (const float*)d_in[6];
  const float* wp1  = (const float*)d_in[7];  const float* bp1 = (const float*)d_in[8];
  const float* wq2  = (const float*)d_in[9];  const float* bq2 = (const float*)d_in[10];
  const float* wk2  = (const float*)d_in[11]; const float* bk2 = (const float*)d_in[12];
  const float* wv2  = (const float*)d_in[13]; const float* bv2 = (const float*)d_in[14];
  const float* wp2  = (const float*)d_in[15]; const float* bp2 = (const float*)d_in[16];
  const float* pegw = (const float*)d_in[17]; const float* pegb = (const float*)d_in[18];
  const float* ln1g = (const float*)d_in[19]; const float* ln1b = (const float*)d_in[20];
  const float* mlng = (const float*)d_in[21]; const float* mlnb = (const float*)d_in[22];
  const float* w1   = (const float*)d_in[23]; const float* b1  = (const float*)d_in[24];
  const float* w2   = (const float*)d_in[25]; const float* b2  = (const float*)d_in[26];
  const float* ln2g = (const float*)d_in[27]; const float* ln2b = (const float*)d_in[28];
  const float* a1   = (const float*)d_in[29];
  const float* a2   = (const float*)d_in[30];
  const float* a3   = (const float*)d_in[31];

  char* ws = (char*)d_ws;
  const long SZ_XF  = 8192L*384*4;
  const long SZ_XB  = 8192L*384*2;
  const long SZ_QK  = 8L*8*1024*96*2;
  const long SZ_YT  = 8L*384*8192*2;
  const long SZ_S2  = 8L*1024*8192*2;
  const long SZ_WQKT= 1536L*384*2;
  const long SZ_WCT = 3072L*384*2;
  const long SZ_WPT = 8L*384*384*2;
  const long SZ_W1T = 768L*384*2;
  const long SZ_W2T = 384L*768*2;

  long off = 0;
  float* xf   = (float*)(ws+off); off += SZ_XF;
  float* xf2  = (float*)(ws+off); off += SZ_XF;
  u16*   xb   = (u16*)  (ws+off); off += SZ_XB;
  u16*   qb   = (u16*)  (ws+off); off += SZ_QK;
  u16*   kb   = (u16*)  (ws+off); off += SZ_QK;
  u16*   Yt   = (u16*)  (ws+off); off += SZ_YT;
  u16*   S2   = (u16*)  (ws+off); off += SZ_S2;
  u16*   wqkT0= (u16*)  (ws+off); off += SZ_WQKT;
  u16*   wqkT1= (u16*)  (ws+off); off += SZ_WQKT;
  u16*   wcT0 = (u16*)  (ws+off); off += SZ_WCT;
  u16*   wcT1 = (u16*)  (ws+off); off += SZ_WCT;
  u16*   w1T  = (u16*)  (ws+off); off += SZ_W1T;
  u16*   w2T  = (u16*)  (ws+off); off += SZ_W2T;
  float* bqkf0= (float*)(ws+off); off += 1536*4;
  float* bqkf1= (float*)(ws+off); off += 1536*4;
  float* bcf0 = (float*)(ws+off); off += 3072*4;
  float* bcf1 = (float*)(ws+off); off += 3072*4;
  float* b1f  = (float*)(ws+off); off += 768*4;
  float* b2f  = (float*)(ws+off); off += 384*4;
  (void)in_sizes; (void)n_in; (void)out_size; (void)ws_size;
  // temporally-disjoint aliases:
  u16*   wpT0 = S2;
  u16*   wpT1 = S2 + SZ_WPT/2;
  u16*   wvb0 = S2 + SZ_WPT;
  u16*   wvb1 = S2 + SZ_WPT + SZ_WPT/2;
  float* xo   = (float*)qb;
  float* h2f  = (float*)kb;
  u16*   hb   = kb;
  u16*   hidb = Yt;

  // ---- prep
  prep_all_k<<<25362,256,0,stream>>>(wq1,wk1,bq1,bk1, wq2,wk2,bq2,bk2, wp1,wp2, wv1,wv2,
                                     w1,b1,w2,b2,
                                     wqkT0,wqkT1,wpT0,wpT1,wvb0,wvb1,w1T,w2T,bqkf0,bqkf1,b1f,b2f);
  bcomb_k<<<12,256,0,stream>>>(bv1, wp1, bcf0);
  bcomb_k<<<12,256,0,stream>>>(bv2, wp2, bcf1);
  gemm_k<0><<<dim3(3,3,8),256,0,stream>>>(wpT0,384,147456, wvb0,384,147456, nullptr,
                                          wcT0,nullptr, 147456, 384, 384);
  gemm_k<0><<<dim3(3,3,8),256,0,stream>>>(wpT1,384,147456, wvb1,384,147456, nullptr,
                                          wcT1,nullptr, 147456, 384, 384);
  t0_k<<<dim3(16,6,8),256,0,stream>>>(dec, xf, xb);

  // ---- layer 1
  gemm_k<1><<<dim3(64,12,1),256,0,stream>>>(xb,384,0, wqkT0,384,0, bqkf0, qb,kb, 0, 384, 0);
  gemm_k<2><<<dim3(64,24,1),256,0,stream>>>(xb,384,0, wcT0,384,0, bcf0, Yt,nullptr, 0, 384, 0);
  gemm_s_k<<<4096,256,0,stream>>>(qb, kb, S2);
  init_k<<<3072,256,0,stream>>>(xf, a1, bp1, xo);
  gemm_big_k<<<256,512,0,stream>>>(S2, Yt, xo);
  peg_ln_k<<<2048,256,0,stream>>>(xo, pegw, pegb, ln1g, ln1b, xf2, xb);

  // ---- layer 2
  gemm_k<1><<<dim3(64,12,1),256,0,stream>>>(xb,384,0, wqkT1,384,0, bqkf1, qb,kb, 0, 384, 0);
  gemm_k<2><<<dim3(64,24,1),256,0,stream>>>(xb,384,0, wcT1,384,0, bcf1, Yt,nullptr, 0, 384, 0);
  gemm_s_k<<<4096,256,0,stream>>>(qb, kb, S2);
  init_k<<<3072,256,0,stream>>>(xf2, a2, bp2, xo);
  gemm_big_k<<<256,512,0,stream>>>(S2, Yt, xo);

  // ---- MLP + final
  ln_k<<<8192,64,0,stream>>>(xo, mlng, mlnb, hb);
  gemm_k<3><<<dim3(64,6,1),256,0,stream>>>(hb,384,0, w1T,384,0, b1f, hidb,nullptr, 0, 384, 768);
  gemm_k<4><<<dim3(64,3,1),256,0,stream>>>(hidb,768,0, w2T,768,0, b2f, h2f,nullptr, 0, 768, 384);
  f1_k<<<8192,64,0,stream>>>(xo, h2f, a3, ln2g, ln2b, xf);
  f2_k<<<dim3(16,6,8),256,0,stream>>>(xf, (float*)d_out);
}

// Round 16
// 523.959 us; speedup vs baseline: 1.0695x; 1.0695x over previous
//
#include <hip/hip_runtime.h>
#include <math.h>

typedef unsigned short u16;
typedef unsigned int u32;
typedef short bh8 __attribute__((ext_vector_type(8)));
typedef float f4 __attribute__((ext_vector_type(4)));

__device__ __forceinline__ float bs2f(u16 s){
  union {unsigned int u; float f;} v; v.u = ((unsigned int)s)<<16; return v.f;
}
__device__ __forceinline__ u16 f2bs(float f){
  union {float f; unsigned int u;} v; v.f = f;
  unsigned int u = v.u + 0x7fffu + ((v.u>>16)&1u);
  return (u16)(u>>16);
}

// ---------------------------------------------------------------- prep
__global__ void prep_all_k(
  const float* __restrict__ wq1,const float* __restrict__ wk1,const float* __restrict__ bq1,const float* __restrict__ bk1,
  const float* __restrict__ wq2,const float* __restrict__ wk2,const float* __restrict__ bq2,const float* __restrict__ bk2,
  const float* __restrict__ wp1,const float* __restrict__ wp2,
  const float* __restrict__ wv1,const float* __restrict__ wv2,
  const float* __restrict__ w1,const float* __restrict__ b1,const float* __restrict__ w2,const float* __restrict__ b2,
  u16* __restrict__ wqkT0,u16* __restrict__ wqkT1,u16* __restrict__ wpT0,u16* __restrict__ wpT1,
  u16* __restrict__ wvb0,u16* __restrict__ wvb1,
  u16* __restrict__ w1T,u16* __restrict__ w2T,
  float* __restrict__ bqkf0,float* __restrict__ bqkf1,float* __restrict__ b1f,float* __restrict__ b2f)
{
  int t = blockIdx.x*256 + threadIdx.x;
  const int S_wqk = 1536*384, S_wp = 8*384*384, S_w1 = 768*384, S_w2 = 384*768;
  if (t < 2*S_wqk){
    const float* wq = (t<S_wqk)? wq1:wq2; const float* wk = (t<S_wqk)? wk1:wk2;
    u16* o = (t<S_wqk)? wqkT0:wqkT1; int i = (t<S_wqk)? t : t-S_wqk;
    int d = i%384, cidx = i/384;
    int c2 = (cidx<768)? cidx : cidx-768;
    int h = c2/96, e = c2-h*96;
    const float* src = (cidx<768)? wq : wk;
    o[i] = f2bs(src[(h*384+d)*96 + e]);
    return;
  }
  t -= 2*S_wqk;
  if (t < 2*S_wp){   // wpT[h][fp][f] = wp[h*384+f][fp]
    const float* wp = (t<S_wp)? wp1:wp2; u16* o = (t<S_wp)? wpT0:wpT1;
    int i = (t<S_wp)? t: t-S_wp;
    int f = i%384; int r = i/384; int fp = r%384; int h = r/384;
    o[i] = f2bs(wp[(h*384+f)*384 + fp]);
    return;
  }
  t -= 2*S_wp;
  if (t < 2*S_wp){   // wvb = bf16 copy of wv [h][d][f]
    const float* wvs = (t<S_wp)? wv1:wv2; u16* o = (t<S_wp)? wvb0:wvb1;
    int i = (t<S_wp)? t: t-S_wp;
    o[i] = f2bs(wvs[i]);
    return;
  }
  t -= 2*S_wp;
  if (t < S_w1){ int d = t%384, hid = t/384; w1T[t] = f2bs(w1[d*768+hid]); return; }
  t -= S_w1;
  if (t < S_w2){ int hid = t%768, dd = t/768; w2T[t] = f2bs(w2[hid*384+dd]); return; }
  t -= S_w2;
  if (t < 1536){ bqkf0[t] = (t<768)? bq1[t] : bk1[t-768]; return; }
  t -= 1536;
  if (t < 1536){ bqkf1[t] = (t<768)? bq2[t] : bk2[t-768]; return; }
  t -= 1536;
  if (t < 768){ b1f[t] = b1[t]; return; }
  t -= 768;
  if (t < 384){ b2f[t] = b2[t]; return; }
}

// bcf[h][fp] = sum_f bv_h[f] * wp[h*384+f][fp]
__global__ void bcomb_k(const float* __restrict__ bv, const float* __restrict__ wp, float* __restrict__ out)
{
  int i = blockIdx.x*256 + threadIdx.x;
  if (i >= 3072) return;
  int h = i/384, fp = i-h*384;
  float s = 0.f;
  for (int f=0; f<384; f++) s += bv[h*384+f] * wp[(h*384+f)*384 + fp];
  out[i] = s;
}

// decoder f32 [B,C,1024] -> xf f32 [B,1024,C] + xb bf16
__global__ void t0_k(const float* __restrict__ dec, float* __restrict__ xf, u16* __restrict__ xb)
{
  int b = blockIdx.z, c0 = blockIdx.y*64, n0 = blockIdx.x*64;
  __shared__ float ts[64][65];
  for (int it=threadIdx.x; it<4096; it+=256){
    int r = it>>6, cc = it&63;
    ts[r][cc] = dec[((long)(b*384 + c0+r)<<10) + n0+cc];
  }
  __syncthreads();
  for (int it=threadIdx.x; it<4096; it+=256){
    int r = it>>6, cc = it&63;
    float s = ts[cc][r];
    long o = ((long)((b<<10)+n0+r))*384 + c0+cc;
    xb[o] = f2bs(s); xf[o] = s;
  }
}

// ---------------------------------------------------------------- generic bf16 MFMA GEMM, 128x128 tile, BK=64
// m97 staging: global_load_lds width-16, pre-swizzled source, swizzled ds_read.
template<int EPI>
__global__ __launch_bounds__(256,2) void gemm_k(
    const u16* __restrict__ A, int lda, long sA,
    const u16* __restrict__ BT, int ldb, long sB,
    const float* __restrict__ bias,
    void* __restrict__ out0, void* __restrict__ out1,
    long sO, int K, int ldc)
{
  __shared__ __align__(16) u16 As[128*64];
  __shared__ __align__(16) u16 Bs[128*64];
  __shared__ __align__(16) u16 Cs[(EPI==2)?128*144:8];
  const int z = blockIdx.z;
  const u16* Ab = A + (long)z*sA;
  const u16* Bb = BT + (long)z*sB;
  const int m0 = blockIdx.x*128, n0 = blockIdx.y*128;
  const int tid = threadIdx.x, lane = tid&63, wv = tid>>6;
  const int wr = wv>>1, wc = wv&1;
  const int stg_r = lane>>3;
  const int stg_u = (lane&7) ^ (lane>>3);
  f4 acc[4][4];
  #pragma unroll
  for (int i=0;i<4;i++)
    #pragma unroll
    for (int j=0;j<4;j++) acc[i][j] = (f4){0.f,0.f,0.f,0.f};
  for (int k0=0;k0<K;k0+=64){
    __syncthreads();
    #pragma unroll
    for (int q=0;q<4;q++){
      int rg = (wv*4+q)*8 + stg_r;
      const u16* ga = Ab + (long)(m0+rg)*lda + k0 + stg_u*8;
      const u16* gb = Bb + (long)(n0+rg)*ldb + k0 + stg_u*8;
      __builtin_amdgcn_global_load_lds(
        (const __attribute__((address_space(1))) unsigned int*)ga,
        (__attribute__((address_space(3))) unsigned int*)(As + (wv*4+q)*512), 16, 0, 0);
      __builtin_amdgcn_global_load_lds(
        (const __attribute__((address_space(1))) unsigned int*)gb,
        (__attribute__((address_space(3))) unsigned int*)(Bs + (wv*4+q)*512), 16, 0, 0);
    }
    __syncthreads();
    #pragma unroll
    for (int ts=0;ts<2;ts++){
      const int sl = ((ts*4 + (lane>>4)) ^ (lane&7))*8;
      bh8 af[4], bfr[4];
      #pragma unroll
      for (int i=0;i<4;i++) af[i] = *(const bh8*)&As[(wr*64+i*16+(lane&15))*64 + sl];
      #pragma unroll
      for (int j=0;j<4;j++) bfr[j] = *(const bh8*)&Bs[(wc*64+j*16+(lane&15))*64 + sl];
      #pragma unroll
      for (int i=0;i<4;i++)
        #pragma unroll
        for (int j=0;j<4;j++)
          acc[i][j] = __builtin_amdgcn_mfma_f32_16x16x32_bf16(af[i], bfr[j], acc[i][j], 0,0,0);
    }
  }
  if constexpr (EPI==0){           // plain bf16 row-major
    u16* O = (u16*)out0 + (long)z*sO;
    #pragma unroll
    for (int i=0;i<4;i++)
      #pragma unroll
      for (int j=0;j<4;j++)
        #pragma unroll
        for (int r=0;r<4;r++){
          int m = m0 + wr*64 + i*16 + ((lane>>4)<<2) + r;
          int n = n0 + wc*64 + j*16 + (lane&15);
          O[(long)m*ldc + n] = f2bs(acc[i][j][r]);
        }
  } else if constexpr (EPI==1){    // QK scatter, +bias
    u16* Q = (u16*)out0; u16* Ko = (u16*)out1;
    #pragma unroll
    for (int j=0;j<4;j++){
      int n = n0 + wc*64 + j*16 + (lane&15);
      float bv = bias[n];
      bool isQ = n < 768; int cc = isQ ? n : n-768;
      int h = cc/96, e = cc - h*96;
      u16* dst = isQ ? Q : Ko;
      #pragma unroll
      for (int i=0;i<4;i++)
        #pragma unroll
        for (int r=0;r<4;r++){
          int m = m0 + wr*64 + i*16 + ((lane>>4)<<2) + r;
          int bb = m>>10, nn = m&1023;
          dst[((long)((bb*8+h)*1024 + nn))*96 + e] = f2bs(acc[i][j][r]+bv);
        }
    }
  } else if constexpr (EPI==2){    // transpose-store Yt[b][f][h*1024+m], +bias (bcf)
    __syncthreads();
    #pragma unroll
    for (int j=0;j<4;j++){
      int nl = wc*64 + j*16 + (lane&15);
      float bv = bias[n0+nl];
      #pragma unroll
      for (int i=0;i<4;i++)
        #pragma unroll
        for (int r=0;r<4;r++){
          int ml = wr*64 + i*16 + ((lane>>4)<<2) + r;
          Cs[nl*144 + ml] = f2bs(acc[i][j][r]+bv);
        }
    }
    __syncthreads();
    u16* O = (u16*)out0;
    const int bb = m0>>10, mb = m0&1023;
    #pragma unroll
    for (int p=0;p<8;p++){
      int row = p*16 + (tid>>4), mcol = (tid&15)*8;
      bh8 vv = *(const bh8*)&Cs[row*144 + mcol];
      int n = n0 + row; int h = n/384, f = n - h*384;
      *(bh8*)(O + (long)bb*3145728 + (long)f*8192 + h*1024 + mb + mcol) = vv;
    }
  } else if constexpr (EPI==3){    // +bias, exact gelu, bf16 row-major
    u16* O = (u16*)out0;
    #pragma unroll
    for (int j=0;j<4;j++){
      int n = n0 + wc*64 + j*16 + (lane&15);
      float bv = bias[n];
      #pragma unroll
      for (int i=0;i<4;i++)
        #pragma unroll
        for (int r=0;r<4;r++){
          int m = m0 + wr*64 + i*16 + ((lane>>4)<<2) + r;
          float v = acc[i][j][r] + bv;
          v = 0.5f*v*(1.0f + erff(v*0.70710678118f));
          O[(long)m*ldc + n] = f2bs(v);
        }
    }
  } else {                         // EPI==4: +bias, f32 row-major
    float* O = (float*)out0;
    #pragma unroll
    for (int j=0;j<4;j++){
      int n = n0 + wc*64 + j*16 + (lane&15);
      float bv = bias[n];
      #pragma unroll
      for (int i=0;i<4;i++)
        #pragma unroll
        for (int r=0;r<4;r++){
          int m = m0 + wr*64 + i*16 + ((lane>>4)<<2) + r;
          O[(long)m*ldc + n] = acc[i][j][r] + bv;
        }
    }
  }
}

// ---------------------------------------------------------------- gemm_s: S2[b][n][h*1024+m] = sigmoid(scale * Q.K)
__global__ __launch_bounds__(256,2) void gemm_s_k(
  const u16* __restrict__ q, const u16* __restrict__ kk_, u16* __restrict__ S2)
{
  __shared__ __align__(16) u16 smem[128*136];
  u16* As = smem;
  u16* Bs = smem + 128*56;
  const int wg = blockIdx.x;
  const int b = wg&7, idx = wg>>3;
  const int h = idx>>6, rem = idx&63;
  const int m0 = (rem>>3)*128;
  const int n0 = (rem&7)*128;
  const u16* Ab = q   + ((long)(b*8+h)<<10)*96;
  const u16* Bb = kk_ + ((long)(b*8+h)<<10)*96;
  const int tid = threadIdx.x, lane = tid&63, wv = tid>>6;
  const int wr = wv>>1, wc = wv&1;
  f4 acc[4][4];
  #pragma unroll
  for (int i=0;i<4;i++)
    #pragma unroll
    for (int j=0;j<4;j++) acc[i][j] = (f4){0.f,0.f,0.f,0.f};
  for (int k0=0;k0<96;k0+=32){
    __syncthreads();
    #pragma unroll
    for (int u=0;u<2;u++){
      int c = tid + u*256;
      int row = c>>2, col8 = (c&3)*8;
      *(bh8*)&As[row*56+col8] = *(const bh8*)(Ab + (long)(m0+row)*96 + k0 + col8);
      *(bh8*)&Bs[row*56+col8] = *(const bh8*)(Bb + (long)(n0+row)*96 + k0 + col8);
    }
    __syncthreads();
    bh8 af[4], bfr[4];
    #pragma unroll
    for (int i=0;i<4;i++) af[i] = *(const bh8*)&As[(wr*64+i*16+(lane&15))*56 + (lane>>4)*8];
    #pragma unroll
    for (int j=0;j<4;j++) bfr[j] = *(const bh8*)&Bs[(wc*64+j*16+(lane&15))*56 + (lane>>4)*8];
    #pragma unroll
    for (int i=0;i<4;i++)
      #pragma unroll
      for (int j=0;j<4;j++)
        acc[i][j] = __builtin_amdgcn_mfma_f32_16x16x32_bf16(af[i], bfr[j], acc[i][j], 0,0,0);
  }
  const float scale = 0.1020620726f;  // 1/sqrt(96)
  __syncthreads();
  #pragma unroll
  for (int j=0;j<4;j++){
    int col = wc*64 + j*16 + (lane&15);
    #pragma unroll
    for (int i=0;i<4;i++)
      #pragma unroll
      for (int r=0;r<4;r++){
        int row = wr*64 + i*16 + ((lane>>4)<<2) + r;
        float y = acc[i][j][r]*scale;
        float sg = __builtin_amdgcn_rcpf(1.0f + __expf(-y));
        smem[row*136 + col] = f2bs(sg);
      }
  }
  __syncthreads();
  u16* O = S2 + (long)b*8388608 + (long)h*1024;
  #pragma unroll
  for (int p=0;p<8;p++){
    int c = tid + p*256;
    int row = c>>4, u = c&15;
    *(bh8*)(O + (long)(m0+row)*8192 + n0 + u*8) = *(const bh8*)&smem[row*136 + u*8];
  }
}

// ---------------------------------------------------------------- init: xo = a*x + bp   (f32 elementwise)
__global__ void init_k(const float* __restrict__ xin, const float* __restrict__ av,
                       const float* __restrict__ bpv, float* __restrict__ xo)
{
  int i = blockIdx.x*256 + threadIdx.x;
  long idx = (long)i*4;
  int c = (int)(idx % 384);
  f4 x = *(const f4*)(xin + idx);
  f4 o;
  #pragma unroll
  for (int kk=0;kk<4;kk++) o[kk] = av[c+kk]*x[kk] + bpv[c+kk];
  *(f4*)(xo + idx) = o;
}

// ---------------------------------------------------------------- gemm_big: xo += S2[b] @ YtAug[b]^T  (split-K=4, atomic)
// M=1024, N=384, K=8192 per b, split-K=4 (2048 each), BK=64.
// grid 768 1D: b=wg&7 (XCD pin), t=wg>>3: ks=t&3, nt=(t>>2)%3, mt=t/12.
__global__ __launch_bounds__(256,2) void gemm_big_k(
  const u16* __restrict__ S2, const u16* __restrict__ Yt, float* __restrict__ xo)
{
  __shared__ __align__(16) u16 As[128*64];
  __shared__ __align__(16) u16 Bs[128*64];
  const int wg = blockIdx.x;
  const int b = wg&7, t = wg>>3;
  const int ks = t&3, nt = (t>>2)%3, mt = t/12;
  const int m0 = mt*128, n0 = nt*128, kb0 = ks*2048;
  const u16* Ab = S2 + (long)b*8388608;   // [1024][8192]
  const u16* Bb = Yt + (long)b*3145728;   // [384][8192]
  const int tid = threadIdx.x, lane = tid&63, wv = tid>>6;
  const int wr = wv>>1, wc = wv&1;
  const int stg_r = lane>>3;
  const int stg_u = (lane&7) ^ (lane>>3);
  f4 acc[4][4];
  #pragma unroll
  for (int i=0;i<4;i++)
    #pragma unroll
    for (int j=0;j<4;j++) acc[i][j] = (f4){0.f,0.f,0.f,0.f};
  for (int k0=kb0; k0<kb0+2048; k0+=64){
    __syncthreads();
    #pragma unroll
    for (int q=0;q<4;q++){
      int rg = (wv*4+q)*8 + stg_r;
      const u16* ga = Ab + (((long)(m0+rg))<<13) + k0 + stg_u*8;
      const u16* gb = Bb + (((long)(n0+rg))<<13) + k0 + stg_u*8;
      __builtin_amdgcn_global_load_lds(
        (const __attribute__((address_space(1))) unsigned int*)ga,
        (__attribute__((address_space(3))) unsigned int*)(As + (wv*4+q)*512), 16, 0, 0);
      __builtin_amdgcn_global_load_lds(
        (const __attribute__((address_space(1))) unsigned int*)gb,
        (__attribute__((address_space(3))) unsigned int*)(Bs + (wv*4+q)*512), 16, 0, 0);
    }
    __syncthreads();
    #pragma unroll
    for (int ts=0;ts<2;ts++){
      const int sl = ((ts*4 + (lane>>4)) ^ (lane&7))*8;
      bh8 af[4], bfr[4];
      #pragma unroll
      for (int i=0;i<4;i++) af[i] = *(const bh8*)&As[(wr*64+i*16+(lane&15))*64 + sl];
      #pragma unroll
      for (int j=0;j<4;j++) bfr[j] = *(const bh8*)&Bs[(wc*64+j*16+(lane&15))*64 + sl];
      #pragma unroll
      for (int i=0;i<4;i++)
        #pragma unroll
        for (int j=0;j<4;j++)
          acc[i][j] = __builtin_amdgcn_mfma_f32_16x16x32_bf16(af[i], bfr[j], acc[i][j], 0,0,0);
    }
  }
  #pragma unroll
  for (int j=0;j<4;j++){
    int n = n0 + wc*64 + j*16 + (lane&15);
    #pragma unroll
    for (int i=0;i<4;i++)
      #pragma unroll
      for (int r=0;r<4;r++){
        int m = m0 + wr*64 + i*16 + ((lane>>4)<<2) + r;
        long o = ((long)((b<<10)+m))*384 + n;
        atomicAdd(&xo[o], acc[i][j][r]);
      }
  }
}

// ---------------------------------------------------------------- peg+LN, wave-per-row, no LDS
__global__ __launch_bounds__(256) void peg_ln_k(
  const float* __restrict__ xin, const float* __restrict__ pw, const float* __restrict__ pb,
  const float* __restrict__ g, const float* __restrict__ bta,
  float* __restrict__ xo, u16* __restrict__ xbo)
{
  const int row = blockIdx.x*4 + (threadIdx.x>>6);
  const int lane = threadIdx.x&63;
  const int b = row>>10, n = row&1023;
  const int i = n>>5, j = n&31;
  const float* xb_ = xin + ((long)(b<<10))*384;
  float v[6]; float s1=0.f, s2=0.f;
  #pragma unroll
  for (int kk=0;kk<6;kk++){
    int c = lane + kk*64;
    float sum = pb[c];
    #pragma unroll
    for (int di=-1; di<=1; di++){
      int ii = i+di; if (ii<0 || ii>31) continue;
      #pragma unroll
      for (int dj=-1; dj<=1; dj++){
        int jj = j+dj; if (jj<0 || jj>31) continue;
        sum += pw[c*9 + (di+1)*3 + (dj+1)] * xb_[(long)(ii*32+jj)*384 + c];
      }
    }
    v[kk] = sum; s1 += sum; s2 += sum*sum;
  }
  #pragma unroll
  for (int m=1;m<64;m<<=1){ s1 += __shfl_xor(s1,m); s2 += __shfl_xor(s2,m); }
  float mu = s1*(1.f/384.f);
  float var = s2*(1.f/384.f) - mu*mu;
  float rsq = rsqrtf(var + 1e-5f);
  long rb = (long)row*384;
  #pragma unroll
  for (int kk=0;kk<6;kk++){
    int c = lane + kk*64;
    float vv = (v[kk]-mu)*rsq*g[c] + bta[c];
    xo[rb+c] = vv; xbo[rb+c] = f2bs(vv);
  }
}

// row LN (f32 in) -> bf16 out
__global__ void ln_k(const float* __restrict__ x, const float* __restrict__ g,
                     const float* __restrict__ bb, u16* __restrict__ ob)
{
  long row = blockIdx.x; int l = threadIdx.x;
  const float* xr = x + row*384;
  float v[6]; float s1=0.f, s2=0.f;
  #pragma unroll
  for (int kk=0;kk<6;kk++){ int c=l+kk*64; float t=xr[c]; v[kk]=t; s1+=t; s2+=t*t; }
  #pragma unroll
  for (int m=1;m<64;m<<=1){ s1 += __shfl_xor(s1,m); s2 += __shfl_xor(s2,m); }
  float mu = s1*(1.f/384.f);
  float var = s2*(1.f/384.f) - mu*mu;
  float rsq = rsqrtf(var + 1e-5f);
  u16* orow = ob + row*384;
  #pragma unroll
  for (int kk=0;kk<6;kk++){ int c=l+kk*64; orow[c] = f2bs((v[kk]-mu)*rsq*g[c] + bb[c]); }
}

// v = a3*x + h2 ; LN2 ; write f32 vbuf
__global__ void f1_k(const float* __restrict__ xf2, const float* __restrict__ h2f,
                     const float* __restrict__ a3, const float* __restrict__ g,
                     const float* __restrict__ bb, float* __restrict__ vb)
{
  long row = blockIdx.x; int l = threadIdx.x;
  const float* xr = xf2 + row*384; const float* hr = h2f + row*384;
  float v[6]; float s1=0.f, s2=0.f;
  #pragma unroll
  for (int kk=0;kk<6;kk++){ int c=l+kk*64; float t = a3[c]*xr[c] + hr[c]; v[kk]=t; s1+=t; s2+=t*t; }
  #pragma unroll
  for (int m=1;m<64;m<<=1){ s1 += __shfl_xor(s1,m); s2 += __shfl_xor(s2,m); }
  float mu = s1*(1.f/384.f);
  float var = s2*(1.f/384.f) - mu*mu;
  float rsq = rsqrtf(var + 1e-5f);
  float* orow = vb + row*384;
  #pragma unroll
  for (int kk=0;kk<6;kk++){ int c=l+kk*64; orow[c] = (v[kk]-mu)*rsq*g[c] + bb[c]; }
}

// vbuf [B,1024,384] f32 -> d_out [B,384,1024] f32
__global__ void f2_k(const float* __restrict__ v, float* __restrict__ o)
{
  int b = blockIdx.z, c0 = blockIdx.y*64, n0 = blockIdx.x*64;
  __shared__ float tile[64][65];
  for (int it=threadIdx.x; it<4096; it+=256){
    int r = it>>6, cc = it&63;
    tile[r][cc] = v[((long)((b<<10)+n0+r))*384 + c0+cc];
  }
  __syncthreads();
  for (int it=threadIdx.x; it<4096; it+=256){
    int r = it>>6, cc = it&63;
    o[((long)(b*384 + c0+r)<<10) + n0+cc] = tile[cc][r];
  }
}

// ---------------------------------------------------------------- launch
extern "C" void kernel_launch(void* const* d_in, const int* in_sizes, int n_in,
                              void* d_out, int out_size, void* d_ws, size_t ws_size,
                              hipStream_t stream)
{
  const float* dec  = (const float*)d_in[0];
  const float* wq1  = (const float*)d_in[1];  const float* bq1 = (const float*)d_in[2];
  const float* wk1  = (const float*)d_in[3];  const float* bk1 = (const float*)d_in[4];
  const float* wv1  = (const float*)d_in[5];  const float* bv1 = (const float*)d_in[6];
  const float* wp1  = (const float*)d_in[7];  const float* bp1 = (const float*)d_in[8];
  const float* wq2  = (const float*)d_in[9];  const float* bq2 = (const float*)d_in[10];
  const float* wk2  = (const float*)d_in[11]; const float* bk2 = (const float*)d_in[12];
  const float* wv2  = (const float*)d_in[13]; const float* bv2 = (const float*)d_in[14];
  const float* wp2  = (const float*)d_in[15]; const float* bp2 = (const float*)d_in[16];
  const float* pegw = (const float*)d_in[17]; const float* pegb = (const float*)d_in[18];
  const float* ln1g = (const float*)d_in[19]; const float* ln1b = (const float*)d_in[20];
  const float* mlng = (const float*)d_in[21]; const float* mlnb = (const float*)d_in[22];
  const float* w1   = (const float*)d_in[23]; const float* b1  = (const float*)d_in[24];
  const float* w2   = (const float*)d_in[25]; const float* b2  = (const float*)d_in[26];
  const float* ln2g = (const float*)d_in[27]; const float* ln2b = (const float*)d_in[28];
  const float* a1   = (const float*)d_in[29];
  const float* a2   = (const float*)d_in[30];
  const float* a3   = (const float*)d_in[31];

  char* ws = (char*)d_ws;
  const long SZ_XF  = 8192L*384*4;
  const long SZ_XB  = 8192L*384*2;
  const long SZ_QK  = 8L*8*1024*96*2;
  const long SZ_YT  = 8L*384*8192*2;
  const long SZ_S2  = 8L*1024*8192*2;
  const long SZ_WQKT= 1536L*384*2;
  const long SZ_WCT = 3072L*384*2;
  const long SZ_WPT = 8L*384*384*2;
  const long SZ_W1T = 768L*384*2;
  const long SZ_W2T = 384L*768*2;

  long off = 0;
  float* xf   = (float*)(ws+off); off += SZ_XF;
  float* xf2  = (float*)(ws+off); off += SZ_XF;
  u16*   xb   = (u16*)  (ws+off); off += SZ_XB;
  u16*   qb   = (u16*)  (ws+off); off += SZ_QK;
  u16*   kb   = (u16*)  (ws+off); off += SZ_QK;
  u16*   Yt   = (u16*)  (ws+off); off += SZ_YT;
  u16*   S2   = (u16*)  (ws+off); off += SZ_S2;
  u16*   wqkT0= (u16*)  (ws+off); off += SZ_WQKT;
  u16*   wqkT1= (u16*)  (ws+off); off += SZ_WQKT;
  u16*   wcT0 = (u16*)  (ws+off); off += SZ_WCT;
  u16*   wcT1 = (u16*)  (ws+off); off += SZ_WCT;
  u16*   w1T  = (u16*)  (ws+off); off += SZ_W1T;
  u16*   w2T  = (u16*)  (ws+off); off += SZ_W2T;
  float* bqkf0= (float*)(ws+off); off += 1536*4;
  float* bqkf1= (float*)(ws+off); off += 1536*4;
  float* bcf0 = (float*)(ws+off); off += 3072*4;
  float* bcf1 = (float*)(ws+off); off += 3072*4;
  float* b1f  = (float*)(ws+off); off += 768*4;
  float* b2f  = (float*)(ws+off); off += 384*4;
  (void)in_sizes; (void)n_in; (void)out_size; (void)ws_size;
  // temporally-disjoint aliases:
  u16*   wpT0 = S2;
  u16*   wpT1 = S2 + SZ_WPT/2;
  u16*   wvb0 = S2 + SZ_WPT;
  u16*   wvb1 = S2 + SZ_WPT + SZ_WPT/2;
  float* xo   = (float*)qb;
  float* h2f  = (float*)kb;
  u16*   hb   = kb;
  u16*   hidb = Yt;

  // ---- prep
  prep_all_k<<<25362,256,0,stream>>>(wq1,wk1,bq1,bk1, wq2,wk2,bq2,bk2, wp1,wp2, wv1,wv2,
                                     w1,b1,w2,b2,
                                     wqkT0,wqkT1,wpT0,wpT1,wvb0,wvb1,w1T,w2T,bqkf0,bqkf1,b1f,b2f);
  bcomb_k<<<12,256,0,stream>>>(bv1, wp1, bcf0);
  bcomb_k<<<12,256,0,stream>>>(bv2, wp2, bcf1);
  gemm_k<0><<<dim3(3,3,8),256,0,stream>>>(wpT0,384,147456, wvb0,384,147456, nullptr,
                                          wcT0,nullptr, 147456, 384, 384);
  gemm_k<0><<<dim3(3,3,8),256,0,stream>>>(wpT1,384,147456, wvb1,384,147456, nullptr,
                                          wcT1,nullptr, 147456, 384, 384);
  t0_k<<<dim3(16,6,8),256,0,stream>>>(dec, xf, xb);

  // ---- layer 1
  gemm_k<1><<<dim3(64,12,1),256,0,stream>>>(xb,384,0, wqkT0,384,0, bqkf0, qb,kb, 0, 384, 0);
  gemm_k<2><<<dim3(64,24,1),256,0,stream>>>(xb,384,0, wcT0,384,0, bcf0, Yt,nullptr, 0, 384, 0);
  gemm_s_k<<<4096,256,0,stream>>>(qb, kb, S2);
  init_k<<<3072,256,0,stream>>>(xf, a1, bp1, xo);
  gemm_big_k<<<768,256,0,stream>>>(S2, Yt, xo);
  peg_ln_k<<<2048,256,0,stream>>>(xo, pegw, pegb, ln1g, ln1b, xf2, xb);

  // ---- layer 2
  gemm_k<1><<<dim3(64,12,1),256,0,stream>>>(xb,384,0, wqkT1,384,0, bqkf1, qb,kb, 0, 384, 0);
  gemm_k<2><<<dim3(64,24,1),256,0,stream>>>(xb,384,0, wcT1,384,0, bcf1, Yt,nullptr, 0, 384, 0);
  gemm_s_k<<<4096,256,0,stream>>>(qb, kb, S2);
  init_k<<<3072,256,0,stream>>>(xf2, a2, bp2, xo);
  gemm_big_k<<<768,256,0,stream>>>(S2, Yt, xo);

  // ---- MLP + final
  ln_k<<<8192,64,0,stream>>>(xo, mlng, mlnb, hb);
  gemm_k<3><<<dim3(64,6,1),256,0,stream>>>(hb,384,0, w1T,384,0, b1f, hidb,nullptr, 0, 384, 768);
  gemm_k<4><<<dim3(64,3,1),256,0,stream>>>(hidb,768,0, w2T,768,0, b2f, h2f,nullptr, 0, 768, 384);
  f1_k<<<8192,64,0,stream>>>(xo, h2f, a3, ln2g, ln2b, xf);
  f2_k<<<dim3(16,6,8),256,0,stream>>>(xf, (float*)d_out);
}